// Round 5
// baseline (10069.834 us; speedup 1.0000x reference)
//
#include <hip/hip_runtime.h>
#include <hip/hip_bf16.h>

typedef _Float16 half8 __attribute__((ext_vector_type(8)));
typedef _Float16 half4 __attribute__((ext_vector_type(4)));
typedef float    floatx4 __attribute__((ext_vector_type(4)));

#define B_TOT 4096
#define L_SEQ 2048
#define H_DIM 256
#define FUT   128
#define T_TOT (L_SEQ + FUT)   /* 2176 */
#define ROWS  8               /* batch rows per block -> 512 blocks = 2 blocks/CU */
#define CHUNK 128             /* x prefetch chunk (steps) */

// tanh(p) = 1 - 2/(e^{2p}+1); exp2 over/underflow saturate to exact +-1.
__device__ __forceinline__ float tanh_fast(float p) {
    float e = __builtin_amdgcn_exp2f(p * 2.885390082f);     // e^(2p)
    return __builtin_fmaf(-2.0f, __builtin_amdgcn_rcpf(e + 1.0f), 1.0f);
}

// Latency-bound recurrence -> maximize independent barrier groups per CU:
// 512 blocks x 8 rows = 2 blocks/CU, 8 waves x 2 N-tiles each (R2's winning
// per-wave shape).  The two co-resident blocks' barriers are unsynchronized,
// so one block's MFMA+epilogue hides under the other's LDS/barrier stalls.
// M=8 of 16 MFMA rows wasted (cheap: MfmaUtil was 25%); lanes 8-15 broadcast-
// read rows 0-7 (same-address LDS = free) and skip stores.
// C = W_tile(A) @ h^T(B): C col = batch row, C row = 4 consecutive neurons ->
// packed ds_write_b64.  lin = 17th MFMA tile on wave 0.  Outputs ring-buffer
// in LDS, coalesced flush every 32 steps.
__global__ __launch_bounds__(512, 4) void rnn_seq_kernel(
    const float* __restrict__ x,      // [B, L]
    const float* __restrict__ W_ih,   // [H]
    const float* __restrict__ b_ih,   // [H]
    const float* __restrict__ W_hh,   // [H, H]
    const float* __restrict__ b_hh,   // [H]
    const float* __restrict__ W_lin,  // [H]
    const float* __restrict__ b_lin,  // [1]
    float* __restrict__ out)          // [B, T_TOT]
{
    __shared__ __align__(16) unsigned char hbuf[2][ROWS * H_DIM * 2]; // fp16 dbuf (4KB each)
    __shared__ __align__(16) float xbuf[CHUNK * 9];                   // [t_local][row] padded
    __shared__ __align__(16) float obuf2[2][32][9];                   // out ring, padded

    const int tid  = threadIdx.x;
    const int l    = tid & 63;
    const int w    = tid >> 6;       // wave 0..7
    const int ln15 = l & 15;
    const int row8 = ln15 & 7;       // batch row this lane's B-frag column maps to
    const int lg   = l >> 4;         // 0..3
    const int b0   = blockIdx.x * ROWS;

    // ---- loop-invariant register state ----
    half8 wf[2][8];                   // W_hh A-frags: 2 N-tiles per wave
    #pragma unroll
    for (int i = 0; i < 2; ++i) {
        const int n = (2 * w + i) * 16 + ln15;
        #pragma unroll
        for (int kk = 0; kk < 8; ++kk) {
            const float* p = W_hh + n * H_DIM + kk * 32 + lg * 8;
            half8 v;
            #pragma unroll
            for (int j = 0; j < 8; ++j) v[j] = (_Float16)p[j];
            wf[i][kk] = v;
        }
    }
    half8 wlf[8];                     // W_lin A-frag (row 0), wave 0 only
    #pragma unroll
    for (int kk = 0; kk < 8; ++kk) {
        const int kbase = kk * 32 + lg * 8;
        half8 v;
        #pragma unroll
        for (int j = 0; j < 8; ++j)
            v[j] = (ln15 == 0) ? (_Float16)W_lin[kbase + j] : (_Float16)0.0f;
        wlf[kk] = v;
    }
    floatx4 wih4[2], bia4[2];
    #pragma unroll
    for (int i = 0; i < 2; ++i) {
        const int n0 = (2 * w + i) * 16 + lg * 4;
        #pragma unroll
        for (int r = 0; r < 4; ++r) {
            wih4[i][r] = W_ih[n0 + r];
            bia4[i][r] = b_ih[n0 + r] + b_hh[n0 + r];
        }
    }
    const float blin = b_lin[0];

    // LDS byte offsets (XOR swizzle bits 4-6 keyed by row&7).  8 rows x 512B.
    int aoff[8];
    #pragma unroll
    for (int kk = 0; kk < 8; ++kk)
        aoff[kk] = (row8 * 512 + kk * 64 + lg * 16) ^ (row8 << 4);
    int woff2[2];
    #pragma unroll
    for (int i = 0; i < 2; ++i)
        woff2[i] = (row8 * 512 + (2 * w + i) * 32 + lg * 8) ^ (row8 << 4);

    // h0 = 0 (8 KB total over 512 threads)
    *(floatx4*)(hbuf[0] + tid * 16) = floatx4{0.f, 0.f, 0.f, 0.f};
    __syncthreads();

    int cur = 0;

    // ============================ main phase ============================
    for (int s = 1; s <= L_SEQ; ++s) {
        const int t_out = s - 2;
        if (t_out >= 32 && (t_out & 31) == 0) {       // coalesced ring flush
            if (tid < 256) {
                const int tb = t_out - 32, par = (tb >> 5) & 1;
                const int r = tid >> 5, tt = tid & 31;
                out[(size_t)(b0 + r) * T_TOT + tb + tt] = obuf2[par][tt][r] + blin;
            }
        }
        if (((s - 1) & (CHUNK - 1)) == 0) {           // x chunk prefetch (1024 elems)
            #pragma unroll
            for (int jj = 0; jj < 2; ++jj) {
                const int idx = jj * 512 + tid;
                const int r = idx >> 7, tl = idx & 127;
                xbuf[tl * 9 + r] = x[(size_t)(b0 + r) * L_SEQ + (s - 1) + tl];
            }
            __syncthreads();
        }
        const float xm = xbuf[((s - 1) & (CHUNK - 1)) * 9 + row8];

        half8 a[8];                                    // B-frags of h_{s-1}
        #pragma unroll
        for (int kk = 0; kk < 8; ++kk)
            a[kk] = *(const half8*)(hbuf[cur] + aoff[kk]);

        // 2 chains per tile; chain0 init = fma(x, W_ih, bias)
        floatx4 acc[2][2];
        #pragma unroll
        for (int i = 0; i < 2; ++i) {
            #pragma unroll
            for (int r = 0; r < 4; ++r)
                acc[i][0][r] = __builtin_fmaf(xm, wih4[i][r], bia4[i][r]);
            acc[i][1] = floatx4{0, 0, 0, 0};
        }
        #pragma unroll
        for (int kk = 0; kk < 8; ++kk) {
            acc[0][kk & 1] = __builtin_amdgcn_mfma_f32_16x16x32_f16(wf[0][kk], a[kk], acc[0][kk & 1], 0, 0, 0);
            acc[1][kk & 1] = __builtin_amdgcn_mfma_f32_16x16x32_f16(wf[1][kk], a[kk], acc[1][kk & 1], 0, 0, 0);
        }
        if (w == 0) {                                  // lin tile
            floatx4 al0 = floatx4{0,0,0,0}, al1 = floatx4{0,0,0,0};
            #pragma unroll
            for (int kk = 0; kk < 8; ++kk) {
                if (kk & 1) al1 = __builtin_amdgcn_mfma_f32_16x16x32_f16(wlf[kk], a[kk], al1, 0, 0, 0);
                else        al0 = __builtin_amdgcn_mfma_f32_16x16x32_f16(wlf[kk], a[kk], al0, 0, 0, 0);
            }
            if (lg == 0 && ln15 < 8 && s >= 2)
                obuf2[(t_out >> 5) & 1][t_out & 31][ln15] = al0[0] + al1[0];
        }
        if (ln15 < 8) {                                // tanh + packed h-write
            #pragma unroll
            for (int i = 0; i < 2; ++i) {
                const floatx4 av = acc[i][0] + acc[i][1];
                half4 hv;
                #pragma unroll
                for (int r = 0; r < 4; ++r) hv[r] = (_Float16)tanh_fast(av[r]);
                *(half4*)(hbuf[cur ^ 1] + woff2[i]) = hv;
            }
        }
        __syncthreads();
        cur ^= 1;
    }

    // ============================ future phase ============================
    for (int s = L_SEQ + 1; s <= T_TOT; ++s) {
        const int t_out = s - 2;
        if ((t_out & 31) == 0) {                       // ring flush
            if (tid < 256) {
                const int tb = t_out - 32, par = (tb >> 5) & 1;
                const int r = tid >> 5, tt = tid & 31;
                out[(size_t)(b0 + r) * T_TOT + tb + tt] = obuf2[par][tt][r] + blin;
            }
        }
        half8 a[8];
        #pragma unroll
        for (int kk = 0; kk < 8; ++kk)
            a[kk] = *(const half8*)(hbuf[cur] + aoff[kk]);

        if (w == 0) {                                  // lin FIRST
            floatx4 al0 = floatx4{0,0,0,0}, al1 = floatx4{0,0,0,0};
            #pragma unroll
            for (int kk = 0; kk < 8; ++kk) {
                if (kk & 1) al1 = __builtin_amdgcn_mfma_f32_16x16x32_f16(wlf[kk], a[kk], al1, 0, 0, 0);
                else        al0 = __builtin_amdgcn_mfma_f32_16x16x32_f16(wlf[kk], a[kk], al0, 0, 0, 0);
            }
            if (lg == 0 && ln15 < 8)
                obuf2[(t_out >> 5) & 1][t_out & 31][ln15] = al0[0] + al1[0];
        }
        floatx4 acc[2][2];
        #pragma unroll
        for (int i = 0; i < 2; ++i) {
            acc[i][0] = bia4[i];
            acc[i][1] = floatx4{0, 0, 0, 0};
        }
        #pragma unroll
        for (int kk = 0; kk < 8; ++kk) {
            acc[0][kk & 1] = __builtin_amdgcn_mfma_f32_16x16x32_f16(wf[0][kk], a[kk], acc[0][kk & 1], 0, 0, 0);
            acc[1][kk & 1] = __builtin_amdgcn_mfma_f32_16x16x32_f16(wf[1][kk], a[kk], acc[1][kk & 1], 0, 0, 0);
        }
        __syncthreads();                               // fed-back output visible
        const float xm = obuf2[(t_out >> 5) & 1][t_out & 31][row8] + blin;

        if (ln15 < 8) {
            #pragma unroll
            for (int i = 0; i < 2; ++i) {
                const floatx4 av = acc[i][0] + acc[i][1];
                half4 hv;
                #pragma unroll
                for (int r = 0; r < 4; ++r)
                    hv[r] = (_Float16)tanh_fast(__builtin_fmaf(xm, wih4[i][r], av[r]));
                *(half4*)(hbuf[cur ^ 1] + woff2[i]) = hv;
            }
        }
        __syncthreads();
        cur ^= 1;
    }

    // final out t = 2175 = lin(h_final): one more lin tile on wave 0
    if (w == 0) {
        half8 a[8];
        #pragma unroll
        for (int kk = 0; kk < 8; ++kk)
            a[kk] = *(const half8*)(hbuf[cur] + aoff[kk]);
        floatx4 al0 = floatx4{0,0,0,0}, al1 = floatx4{0,0,0,0};
        #pragma unroll
        for (int kk = 0; kk < 8; ++kk) {
            if (kk & 1) al1 = __builtin_amdgcn_mfma_f32_16x16x32_f16(wlf[kk], a[kk], al1, 0, 0, 0);
            else        al0 = __builtin_amdgcn_mfma_f32_16x16x32_f16(wlf[kk], a[kk], al0, 0, 0, 0);
        }
        if (lg == 0 && ln15 < 8) obuf2[1][31][ln15] = al0[0] + al1[0];
    }
    __syncthreads();
    if (tid < 256) {   // final flush t = 2144..2175 (parity 1)
        const int r = tid >> 5, tt = tid & 31;
        out[(size_t)(b0 + r) * T_TOT + 2144 + tt] = obuf2[1][tt][r] + blin;
    }
}

extern "C" void kernel_launch(void* const* d_in, const int* in_sizes, int n_in,
                              void* d_out, int out_size, void* d_ws, size_t ws_size,
                              hipStream_t stream) {
    const float* x     = (const float*)d_in[0];
    const float* W_ih  = (const float*)d_in[1];
    const float* b_ih  = (const float*)d_in[2];
    const float* W_hh  = (const float*)d_in[3];
    const float* b_hh  = (const float*)d_in[4];
    const float* W_lin = (const float*)d_in[5];
    const float* b_lin = (const float*)d_in[6];
    float* out = (float*)d_out;
    rnn_seq_kernel<<<B_TOT / ROWS, 512, 0, stream>>>(x, W_ih, b_ih, W_hh, b_hh, W_lin, b_lin, out);
}

// Round 6
// 3062.187 us; speedup vs baseline: 3.2884x; 3.2884x over previous
//
#include <hip/hip_runtime.h>
#include <hip/hip_bf16.h>

typedef _Float16 half8 __attribute__((ext_vector_type(8)));
typedef _Float16 half4 __attribute__((ext_vector_type(4)));
typedef float    floatx4 __attribute__((ext_vector_type(4)));

#define B_TOT 4096
#define L_SEQ 2048
#define H_DIM 256
#define FUT   128
#define T_TOT (L_SEQ + FUT)   /* 2176 */
#define ROWS  8               /* batch rows per block -> 512 blocks = 2 blocks/CU */
#define CHUNK 128             /* x prefetch chunk (steps) */

// tanh(p) = 1 - 2/(e^{2p}+1); exp2 over/underflow saturate to exact +-1.
__device__ __forceinline__ float tanh_fast(float p) {
    float e = __builtin_amdgcn_exp2f(p * 2.885390082f);     // e^(2p)
    return __builtin_fmaf(-2.0f, __builtin_amdgcn_rcpf(e + 1.0f), 1.0f);
}

// Latency-bound recurrence -> maximize independent barrier groups per CU:
// 512 blocks x 8 rows = 2 blocks/CU, 8 waves x 2 N-tiles each.  The two
// co-resident blocks' barriers are unsynchronized, so one block's
// MFMA+epilogue hides under the other's LDS/barrier stalls.
// NOTE: launch_bounds (512, 2) NOT (512, 4) — min-waves/EU=4 caps VGPR at 64
// and spills W_hh to scratch (R5: 3 GB scratch traffic, 10 ms).  At ~108 VGPR
// (cap 256, fits <=128) the HW co-schedules 2 blocks/CU on its own.
__global__ __launch_bounds__(512, 2) void rnn_seq_kernel(
    const float* __restrict__ x,      // [B, L]
    const float* __restrict__ W_ih,   // [H]
    const float* __restrict__ b_ih,   // [H]
    const float* __restrict__ W_hh,   // [H, H]
    const float* __restrict__ b_hh,   // [H]
    const float* __restrict__ W_lin,  // [H]
    const float* __restrict__ b_lin,  // [1]
    float* __restrict__ out)          // [B, T_TOT]
{
    __shared__ __align__(16) unsigned char hbuf[2][ROWS * H_DIM * 2]; // fp16 dbuf (4KB each)
    __shared__ __align__(16) float xbuf[CHUNK * 9];                   // [t_local][row] padded
    __shared__ __align__(16) float obuf2[2][32][9];                   // out ring, padded

    const int tid  = threadIdx.x;
    const int l    = tid & 63;
    const int w    = tid >> 6;       // wave 0..7
    const int ln15 = l & 15;
    const int row8 = ln15 & 7;       // batch row this lane's B-frag column maps to
    const int lg   = l >> 4;         // 0..3
    const int b0   = blockIdx.x * ROWS;

    // ---- loop-invariant register state ----
    half8 wf[2][8];                   // W_hh A-frags: 2 N-tiles per wave
    #pragma unroll
    for (int i = 0; i < 2; ++i) {
        const int n = (2 * w + i) * 16 + ln15;
        #pragma unroll
        for (int kk = 0; kk < 8; ++kk) {
            const float* p = W_hh + n * H_DIM + kk * 32 + lg * 8;
            half8 v;
            #pragma unroll
            for (int j = 0; j < 8; ++j) v[j] = (_Float16)p[j];
            wf[i][kk] = v;
        }
    }
    half8 wlf[8];                     // W_lin A-frag (row 0), wave 0 only
    #pragma unroll
    for (int kk = 0; kk < 8; ++kk) {
        const int kbase = kk * 32 + lg * 8;
        half8 v;
        #pragma unroll
        for (int j = 0; j < 8; ++j)
            v[j] = (ln15 == 0) ? (_Float16)W_lin[kbase + j] : (_Float16)0.0f;
        wlf[kk] = v;
    }
    floatx4 wih4[2], bia4[2];
    #pragma unroll
    for (int i = 0; i < 2; ++i) {
        const int n0 = (2 * w + i) * 16 + lg * 4;
        #pragma unroll
        for (int r = 0; r < 4; ++r) {
            wih4[i][r] = W_ih[n0 + r];
            bia4[i][r] = b_ih[n0 + r] + b_hh[n0 + r];
        }
    }
    const float blin = b_lin[0];

    // LDS byte offsets (XOR swizzle bits 4-6 keyed by row&7).  8 rows x 512B.
    int aoff[8];
    #pragma unroll
    for (int kk = 0; kk < 8; ++kk)
        aoff[kk] = (row8 * 512 + kk * 64 + lg * 16) ^ (row8 << 4);
    int woff2[2];
    #pragma unroll
    for (int i = 0; i < 2; ++i)
        woff2[i] = (row8 * 512 + (2 * w + i) * 32 + lg * 8) ^ (row8 << 4);

    // h0 = 0 (8 KB total over 512 threads)
    *(floatx4*)(hbuf[0] + tid * 16) = floatx4{0.f, 0.f, 0.f, 0.f};
    __syncthreads();

    int cur = 0;

    // ============================ main phase ============================
    for (int s = 1; s <= L_SEQ; ++s) {
        const int t_out = s - 2;
        if (t_out >= 32 && (t_out & 31) == 0) {       // coalesced ring flush
            if (tid < 256) {
                const int tb = t_out - 32, par = (tb >> 5) & 1;
                const int r = tid >> 5, tt = tid & 31;
                out[(size_t)(b0 + r) * T_TOT + tb + tt] = obuf2[par][tt][r] + blin;
            }
        }
        if (((s - 1) & (CHUNK - 1)) == 0) {           // x chunk prefetch (1024 elems)
            #pragma unroll
            for (int jj = 0; jj < 2; ++jj) {
                const int idx = jj * 512 + tid;
                const int r = idx >> 7, tl = idx & 127;
                xbuf[tl * 9 + r] = x[(size_t)(b0 + r) * L_SEQ + (s - 1) + tl];
            }
            __syncthreads();
        }
        const float xm = xbuf[((s - 1) & (CHUNK - 1)) * 9 + row8];

        half8 a[8];                                    // B-frags of h_{s-1}
        #pragma unroll
        for (int kk = 0; kk < 8; ++kk)
            a[kk] = *(const half8*)(hbuf[cur] + aoff[kk]);

        // 2 chains per tile; chain0 init = fma(x, W_ih, bias)
        floatx4 acc[2][2];
        #pragma unroll
        for (int i = 0; i < 2; ++i) {
            #pragma unroll
            for (int r = 0; r < 4; ++r)
                acc[i][0][r] = __builtin_fmaf(xm, wih4[i][r], bia4[i][r]);
            acc[i][1] = floatx4{0, 0, 0, 0};
        }
        #pragma unroll
        for (int kk = 0; kk < 8; ++kk) {
            acc[0][kk & 1] = __builtin_amdgcn_mfma_f32_16x16x32_f16(wf[0][kk], a[kk], acc[0][kk & 1], 0, 0, 0);
            acc[1][kk & 1] = __builtin_amdgcn_mfma_f32_16x16x32_f16(wf[1][kk], a[kk], acc[1][kk & 1], 0, 0, 0);
        }
        if (w == 0) {                                  // lin tile
            floatx4 al0 = floatx4{0,0,0,0}, al1 = floatx4{0,0,0,0};
            #pragma unroll
            for (int kk = 0; kk < 8; ++kk) {
                if (kk & 1) al1 = __builtin_amdgcn_mfma_f32_16x16x32_f16(wlf[kk], a[kk], al1, 0, 0, 0);
                else        al0 = __builtin_amdgcn_mfma_f32_16x16x32_f16(wlf[kk], a[kk], al0, 0, 0, 0);
            }
            if (lg == 0 && ln15 < 8 && s >= 2)
                obuf2[(t_out >> 5) & 1][t_out & 31][ln15] = al0[0] + al1[0];
        }
        if (ln15 < 8) {                                // tanh + packed h-write
            #pragma unroll
            for (int i = 0; i < 2; ++i) {
                const floatx4 av = acc[i][0] + acc[i][1];
                half4 hv;
                #pragma unroll
                for (int r = 0; r < 4; ++r) hv[r] = (_Float16)tanh_fast(av[r]);
                *(half4*)(hbuf[cur ^ 1] + woff2[i]) = hv;
            }
        }
        __syncthreads();
        cur ^= 1;
    }

    // ============================ future phase ============================
    for (int s = L_SEQ + 1; s <= T_TOT; ++s) {
        const int t_out = s - 2;
        if ((t_out & 31) == 0) {                       // ring flush
            if (tid < 256) {
                const int tb = t_out - 32, par = (tb >> 5) & 1;
                const int r = tid >> 5, tt = tid & 31;
                out[(size_t)(b0 + r) * T_TOT + tb + tt] = obuf2[par][tt][r] + blin;
            }
        }
        half8 a[8];
        #pragma unroll
        for (int kk = 0; kk < 8; ++kk)
            a[kk] = *(const half8*)(hbuf[cur] + aoff[kk]);

        if (w == 0) {                                  // lin FIRST
            floatx4 al0 = floatx4{0,0,0,0}, al1 = floatx4{0,0,0,0};
            #pragma unroll
            for (int kk = 0; kk < 8; ++kk) {
                if (kk & 1) al1 = __builtin_amdgcn_mfma_f32_16x16x32_f16(wlf[kk], a[kk], al1, 0, 0, 0);
                else        al0 = __builtin_amdgcn_mfma_f32_16x16x32_f16(wlf[kk], a[kk], al0, 0, 0, 0);
            }
            if (lg == 0 && ln15 < 8)
                obuf2[(t_out >> 5) & 1][t_out & 31][ln15] = al0[0] + al1[0];
        }
        floatx4 acc[2][2];
        #pragma unroll
        for (int i = 0; i < 2; ++i) {
            acc[i][0] = bia4[i];
            acc[i][1] = floatx4{0, 0, 0, 0};
        }
        #pragma unroll
        for (int kk = 0; kk < 8; ++kk) {
            acc[0][kk & 1] = __builtin_amdgcn_mfma_f32_16x16x32_f16(wf[0][kk], a[kk], acc[0][kk & 1], 0, 0, 0);
            acc[1][kk & 1] = __builtin_amdgcn_mfma_f32_16x16x32_f16(wf[1][kk], a[kk], acc[1][kk & 1], 0, 0, 0);
        }
        __syncthreads();                               // fed-back output visible
        const float xm = obuf2[(t_out >> 5) & 1][t_out & 31][row8] + blin;

        if (ln15 < 8) {
            #pragma unroll
            for (int i = 0; i < 2; ++i) {
                const floatx4 av = acc[i][0] + acc[i][1];
                half4 hv;
                #pragma unroll
                for (int r = 0; r < 4; ++r)
                    hv[r] = (_Float16)tanh_fast(__builtin_fmaf(xm, wih4[i][r], av[r]));
                *(half4*)(hbuf[cur ^ 1] + woff2[i]) = hv;
            }
        }
        __syncthreads();
        cur ^= 1;
    }

    // final out t = 2175 = lin(h_final): one more lin tile on wave 0
    if (w == 0) {
        half8 a[8];
        #pragma unroll
        for (int kk = 0; kk < 8; ++kk)
            a[kk] = *(const half8*)(hbuf[cur] + aoff[kk]);
        floatx4 al0 = floatx4{0,0,0,0}, al1 = floatx4{0,0,0,0};
        #pragma unroll
        for (int kk = 0; kk < 8; ++kk) {
            if (kk & 1) al1 = __builtin_amdgcn_mfma_f32_16x16x32_f16(wlf[kk], a[kk], al1, 0, 0, 0);
            else        al0 = __builtin_amdgcn_mfma_f32_16x16x32_f16(wlf[kk], a[kk], al0, 0, 0, 0);
        }
        if (lg == 0 && ln15 < 8) obuf2[1][31][ln15] = al0[0] + al1[0];
    }
    __syncthreads();
    if (tid < 256) {   // final flush t = 2144..2175 (parity 1)
        const int r = tid >> 5, tt = tid & 31;
        out[(size_t)(b0 + r) * T_TOT + 2144 + tt] = obuf2[1][tt][r] + blin;
    }
}

extern "C" void kernel_launch(void* const* d_in, const int* in_sizes, int n_in,
                              void* d_out, int out_size, void* d_ws, size_t ws_size,
                              hipStream_t stream) {
    const float* x     = (const float*)d_in[0];
    const float* W_ih  = (const float*)d_in[1];
    const float* b_ih  = (const float*)d_in[2];
    const float* W_hh  = (const float*)d_in[3];
    const float* b_hh  = (const float*)d_in[4];
    const float* W_lin = (const float*)d_in[5];
    const float* b_lin = (const float*)d_in[6];
    float* out = (float*)d_out;
    rnn_seq_kernel<<<B_TOT / ROWS, 512, 0, stream>>>(x, W_ih, b_ih, W_hh, b_hh, W_lin, b_lin, out);
}

// Round 8
// 1574.318 us; speedup vs baseline: 6.3963x; 1.9451x over previous
//
#include <hip/hip_runtime.h>
#include <hip/hip_bf16.h>

typedef _Float16 half8 __attribute__((ext_vector_type(8)));
typedef _Float16 half4 __attribute__((ext_vector_type(4)));
typedef float    floatx4 __attribute__((ext_vector_type(4)));

#define B_TOT 4096
#define L_SEQ 2048
#define H_DIM 256
#define FUT   128
#define T_TOT (L_SEQ + FUT)   /* 2176 */
#define ROWS  16              /* batch rows per block */
#define CHUNK 128             /* x prefetch chunk (steps) */

// tanh(p) = 1 - 2/(e^{2p}+1); exp2 over/underflow saturate to exact +-1.
__device__ __forceinline__ float tanh_fast(float p) {
    float e = __builtin_amdgcn_exp2f(p * 2.885390082f);     // e^(2p)
    return __builtin_fmaf(-2.0f, __builtin_amdgcn_rcpf(e + 1.0f), 1.0f);
}

// R2 structure (8 waves x 2 N-tiles, swapped-operand MFMA, LDS out-ring) plus:
//  - main-phase lin moved AFTER the barrier on wave 0 (a[] regs survive it):
//    removes the 8-MFMA wave-0 straggler from every step's barrier wait.
//    Flush trigger shifted to (t_out&31)==2 so the post-barrier obuf write is
//    >=2 barriers old before any flush reads it.
//  - W_lin placed in A-rows {0,4,8,12}: al[0] holds lin(h) for batch row ln15
//    in EVERY lane group -> future-phase feedback is in-register, single
//    barrier per future step (obuf only feeds the output flush).
__global__ __launch_bounds__(512, 2) void rnn_seq_kernel(
    const float* __restrict__ x,      // [B, L]
    const float* __restrict__ W_ih,   // [H]
    const float* __restrict__ b_ih,   // [H]
    const float* __restrict__ W_hh,   // [H, H]
    const float* __restrict__ b_hh,   // [H]
    const float* __restrict__ W_lin,  // [H]
    const float* __restrict__ b_lin,  // [1]
    float* __restrict__ out)          // [B, T_TOT]
{
    __shared__ __align__(16) unsigned char hbuf[2][ROWS * H_DIM * 2]; // fp16 dbuf
    __shared__ __align__(16) float xbuf[CHUNK * 17];                  // [t_local][row]
    __shared__ __align__(16) float obuf2[2][32][17];                  // out ring

    const int tid  = threadIdx.x;
    const int l    = tid & 63;
    const int w    = tid >> 6;       // wave 0..7
    const int ln15 = l & 15;
    const int lg   = l >> 4;         // 0..3
    const int b0   = blockIdx.x * ROWS;

    // ---- loop-invariant register state ----
    half8 wf[2][8];                   // W_hh A-frags: 2 N-tiles per wave
    #pragma unroll
    for (int i = 0; i < 2; ++i) {
        const int n = (2 * w + i) * 16 + ln15;
        #pragma unroll
        for (int kk = 0; kk < 8; ++kk) {
            const float* p = W_hh + n * H_DIM + kk * 32 + lg * 8;
            half8 v;
            #pragma unroll
            for (int j = 0; j < 8; ++j) v[j] = (_Float16)p[j];
            wf[i][kk] = v;
        }
    }
    // W_lin A-frag in rows 0,4,8,12 -> C rows 0,4,8,12 all = lin(h):
    // al[0] (reg 0) is valid at every lane group lg.
    half8 wlf[8];
    #pragma unroll
    for (int kk = 0; kk < 8; ++kk) {
        const int kbase = kk * 32 + lg * 8;
        half8 v;
        #pragma unroll
        for (int j = 0; j < 8; ++j)
            v[j] = ((ln15 & 3) == 0) ? (_Float16)W_lin[kbase + j] : (_Float16)0.0f;
        wlf[kk] = v;
    }
    floatx4 wih4[2], bia4[2];
    #pragma unroll
    for (int i = 0; i < 2; ++i) {
        const int n0 = (2 * w + i) * 16 + lg * 4;
        #pragma unroll
        for (int r = 0; r < 4; ++r) {
            wih4[i][r] = W_ih[n0 + r];
            bia4[i][r] = b_ih[n0 + r] + b_hh[n0 + r];
        }
    }
    const float blin = b_lin[0];

    // LDS byte offsets (XOR swizzle bits 4-6 keyed by row&7)
    int aoff[8];
    #pragma unroll
    for (int kk = 0; kk < 8; ++kk)
        aoff[kk] = (ln15 * 512 + kk * 64 + lg * 16) ^ ((ln15 & 7) << 4);
    int woff2[2];
    #pragma unroll
    for (int i = 0; i < 2; ++i)
        woff2[i] = (ln15 * 512 + (2 * w + i) * 32 + lg * 8) ^ ((ln15 & 7) << 4);

    *(floatx4*)(hbuf[0] + tid * 16) = floatx4{0.f, 0.f, 0.f, 0.f};  // h0 = 0
    __syncthreads();

    int cur = 0;

    // ============================ main phase ============================
    for (int s = 1; s <= L_SEQ; ++s) {
        const int t_out = s - 2;

        // flush completed 32-block [t_out-34, t_out-3]: newest entry was
        // written >=2 barriers ago (post-barrier lin writes need the margin)
        if (t_out >= 34 && (t_out & 31) == 2) {
            const int tb = t_out - 34, par = (tb >> 5) & 1;
            const int rr = tid >> 5, tt = tid & 31;
            out[(size_t)(b0 + rr) * T_TOT + tb + tt] = obuf2[par][tt][rr] + blin;
        }
        if (((s - 1) & (CHUNK - 1)) == 0) {           // x chunk prefetch
            #pragma unroll
            for (int jj = 0; jj < 4; ++jj) {
                const int idx = jj * 512 + tid;
                const int rr = idx >> 7, tl = idx & 127;
                xbuf[tl * 17 + rr] = x[(size_t)(b0 + rr) * L_SEQ + (s - 1) + tl];
            }
            __syncthreads();
        }

        half8 a[8];                                    // B-frags of h_{s-1}
        #pragma unroll
        for (int kk = 0; kk < 8; ++kk)
            a[kk] = *(const half8*)(hbuf[cur] + aoff[kk]);
        const float xm = xbuf[((s - 1) & (CHUNK - 1)) * 17 + ln15];

        // 2 chains per tile; chain0 init = fma(x, W_ih, bias)
        floatx4 acc[2][2];
        #pragma unroll
        for (int i = 0; i < 2; ++i) {
            #pragma unroll
            for (int r = 0; r < 4; ++r)
                acc[i][0][r] = __builtin_fmaf(xm, wih4[i][r], bia4[i][r]);
            acc[i][1] = floatx4{0, 0, 0, 0};
        }
        #pragma unroll
        for (int kk = 0; kk < 8; ++kk) {
            acc[0][kk & 1] = __builtin_amdgcn_mfma_f32_16x16x32_f16(wf[0][kk], a[kk], acc[0][kk & 1], 0, 0, 0);
            acc[1][kk & 1] = __builtin_amdgcn_mfma_f32_16x16x32_f16(wf[1][kk], a[kk], acc[1][kk & 1], 0, 0, 0);
        }
        // tanh + packed b64 h-write
        #pragma unroll
        for (int i = 0; i < 2; ++i) {
            const floatx4 av = acc[i][0] + acc[i][1];
            half4 hv;
            #pragma unroll
            for (int r = 0; r < 4; ++r) hv[r] = (_Float16)tanh_fast(av[r]);
            *(half4*)(hbuf[cur ^ 1] + woff2[i]) = hv;
        }
        __syncthreads();

        // lin AFTER the barrier (wave 0 only; a[] regs still hold h_{s-1}):
        // overlaps the other waves' next-step LDS reads instead of delaying
        // this step's barrier.
        if (w == 0 && s >= 2) {
            floatx4 al0 = floatx4{0,0,0,0}, al1 = floatx4{0,0,0,0};
            #pragma unroll
            for (int kk = 0; kk < 8; ++kk) {
                if (kk & 1) al1 = __builtin_amdgcn_mfma_f32_16x16x32_f16(wlf[kk], a[kk], al1, 0, 0, 0);
                else        al0 = __builtin_amdgcn_mfma_f32_16x16x32_f16(wlf[kk], a[kk], al0, 0, 0, 0);
            }
            if (lg == 0)
                obuf2[(t_out >> 5) & 1][t_out & 31][ln15] = al0[0] + al1[0];
        }
        cur ^= 1;
    }

    // ============================ future phase ============================
    // feedback is in-register (al[0] valid in every lane group): 1 barrier/step
    for (int s = L_SEQ + 1; s <= T_TOT; ++s) {
        const int t_out = s - 2;
        if ((t_out & 31) == 2) {                       // ring flush (same margin)
            const int tb = t_out - 34, par = (tb >> 5) & 1;
            const int rr = tid >> 5, tt = tid & 31;
            out[(size_t)(b0 + rr) * T_TOT + tb + tt] = obuf2[par][tt][rr] + blin;
        }
        half8 a[8];
        #pragma unroll
        for (int kk = 0; kk < 8; ++kk)
            a[kk] = *(const half8*)(hbuf[cur] + aoff[kk]);

        // lin(h_{s-1}) on ALL waves (in-register feedback), 2 chains
        floatx4 al0 = floatx4{0,0,0,0}, al1 = floatx4{0,0,0,0};
        #pragma unroll
        for (int kk = 0; kk < 8; ++kk) {
            if (kk & 1) al1 = __builtin_amdgcn_mfma_f32_16x16x32_f16(wlf[kk], a[kk], al1, 0, 0, 0);
            else        al0 = __builtin_amdgcn_mfma_f32_16x16x32_f16(wlf[kk], a[kk], al0, 0, 0, 0);
        }
        floatx4 acc[2][2];
        #pragma unroll
        for (int i = 0; i < 2; ++i) {
            acc[i][0] = bia4[i];
            acc[i][1] = floatx4{0, 0, 0, 0};
        }
        #pragma unroll
        for (int kk = 0; kk < 8; ++kk) {
            acc[0][kk & 1] = __builtin_amdgcn_mfma_f32_16x16x32_f16(wf[0][kk], a[kk], acc[0][kk & 1], 0, 0, 0);
            acc[1][kk & 1] = __builtin_amdgcn_mfma_f32_16x16x32_f16(wf[1][kk], a[kk], acc[1][kk & 1], 0, 0, 0);
        }
        if (w == 0 && lg == 0)                         // output record only
            obuf2[(t_out >> 5) & 1][t_out & 31][ln15] = al0[0] + al1[0];

        const float xm = al0[0] + al1[0] + blin;       // per-lane feedback, row ln15
        #pragma unroll
        for (int i = 0; i < 2; ++i) {
            const floatx4 av = acc[i][0] + acc[i][1];
            half4 hv;
            #pragma unroll
            for (int r = 0; r < 4; ++r)
                hv[r] = (_Float16)tanh_fast(__builtin_fmaf(xm, wih4[i][r], av[r]));
            *(half4*)(hbuf[cur ^ 1] + woff2[i]) = hv;
        }
        __syncthreads();
        cur ^= 1;
    }

    // final out t = 2175 = lin(h_final): one more lin tile on wave 0
    if (w == 0) {
        half8 a[8];
        #pragma unroll
        for (int kk = 0; kk < 8; ++kk)
            a[kk] = *(const half8*)(hbuf[cur] + aoff[kk]);
        floatx4 al0 = floatx4{0,0,0,0}, al1 = floatx4{0,0,0,0};
        #pragma unroll
        for (int kk = 0; kk < 8; ++kk) {
            if (kk & 1) al1 = __builtin_amdgcn_mfma_f32_16x16x32_f16(wlf[kk], a[kk], al1, 0, 0, 0);
            else        al0 = __builtin_amdgcn_mfma_f32_16x16x32_f16(wlf[kk], a[kk], al0, 0, 0, 0);
        }
        if (lg == 0) obuf2[1][31][ln15] = al0[0] + al1[0];
    }
    __syncthreads();
    {   // final flush t = 2144..2175 (parity 1); indices 2144..2174 written
        // in-loop, 2175 just above
        const int rr = tid >> 5, tt = tid & 31;
        out[(size_t)(b0 + rr) * T_TOT + 2144 + tt] = obuf2[1][tt][rr] + blin;
    }
}

extern "C" void kernel_launch(void* const* d_in, const int* in_sizes, int n_in,
                              void* d_out, int out_size, void* d_ws, size_t ws_size,
                              hipStream_t stream) {
    const float* x     = (const float*)d_in[0];
    const float* W_ih  = (const float*)d_in[1];
    const float* b_ih  = (const float*)d_in[2];
    const float* W_hh  = (const float*)d_in[3];
    const float* b_hh  = (const float*)d_in[4];
    const float* W_lin = (const float*)d_in[5];
    const float* b_lin = (const float*)d_in[6];
    float* out = (float*)d_out;
    rnn_seq_kernel<<<B_TOT / ROWS, 512, 0, stream>>>(x, W_ih, b_ih, W_hh, b_hh, W_lin, b_lin, out);
}